// Round 4
// baseline (71.229 us; speedup 1.0000x reference)
//
#include <hip/hip_runtime.h>
#include <stdint.h>

#define HH 512
#define WW 512
#define CC 4
#define BB 8
#define NPIX (BB * HH * WW)   // 2097152
#define NBLK (BB * HH)        // 4096 blocks, one per output row

// min over 4 packed u8 row-distances, squared (exact integers in fp32)
__device__ __forceinline__ float row_min_sq(uint32_t v) {
    float c0 = (float)(v & 255u);
    float c1 = (float)((v >> 8) & 255u);
    float c2 = (float)((v >> 16) & 255u);
    float c3 = (float)(v >> 24);
    return fminf(fminf(c0 * c0, c1 * c1), fminf(c2 * c2, c3 * c3));
}

// exact zero-byte mask: byte==0 -> that byte becomes 0xFF (no borrow FPs)
__device__ __forceinline__ uint32_t own_mask(uint32_t v) {
    uint32_t z = (~((v & 0x7F7F7F7Fu) + 0x7F7F7F7Fu)) & ~v & 0x80808080u;
    return (z >> 7) * 255u;
}

// ---------------------------------------------------------------------------
// Wave-cooperative 1D row distance scan: reads target row (4 ch), writes
// packed u8x4 per-class distances to LDS. Lane l owns columns [8l, 8l+8).
// Must be called by all 64 lanes of a wave together.
// ---------------------------------------------------------------------------
__device__ __forceinline__ void scan_row(const float* __restrict__ trow,
                                         int lane, uint32_t* __restrict__ ldsrow) {
    const int j0 = lane << 3;

    // labels = argmax over channels (one-hot; strict > = first-max semantics)
    int L[8];
    float tm[8];
    #pragma unroll
    for (int c = 0; c < CC; ++c) {
        const float4* p = reinterpret_cast<const float4*>(trow + (size_t)c * (HH * WW) + j0);
        float4 a0 = p[0], a1 = p[1];
        float tv[8] = {a0.x, a0.y, a0.z, a0.w, a1.x, a1.y, a1.z, a1.w};
        #pragma unroll
        for (int jj = 0; jj < 8; ++jj) {
            if (c == 0) { tm[jj] = tv[jj]; L[jj] = 0; }
            else if (tv[jj] > tm[jj]) { tm[jj] = tv[jj]; L[jj] = c; }
        }
    }

    uint32_t gp[8] = {0, 0, 0, 0, 0, 0, 0, 0};
    #pragma unroll
    for (int c = 0; c < CC; ++c) {
        // left: last feature index <= j (local run + wave prefix max)
        int run = -1000000;
        int lastL[8];
        #pragma unroll
        for (int jj = 0; jj < 8; ++jj) { if (L[jj] == c) run = j0 + jj; lastL[jj] = run; }
        int incl = run;
        #pragma unroll
        for (int d = 1; d < 64; d <<= 1) {
            int up = __shfl_up(incl, (unsigned)d, 64);
            if (lane >= d) incl = max(incl, up);
        }
        int excl = __shfl_up(incl, 1u, 64);
        if (lane == 0) excl = -1000000;

        // right: next feature index >= j (reverse prefix min)
        int nrun = 1000000;
        int nxtL[8];
        #pragma unroll
        for (int jj = 7; jj >= 0; --jj) { if (L[jj] == c) nrun = j0 + jj; nxtL[jj] = nrun; }
        int rincl = nrun;
        #pragma unroll
        for (int d = 1; d < 64; d <<= 1) {
            int dn = __shfl_down(rincl, (unsigned)d, 64);
            if (lane < 64 - d) rincl = min(rincl, dn);
        }
        int rexcl = __shfl_down(rincl, 1u, 64);
        if (lane == 63) rexcl = 1000000;

        #pragma unroll
        for (int jj = 0; jj < 8; ++jj) {
            int last = max(lastL[jj], excl);
            int nxt  = min(nxtL[jj], rexcl);
            int gg = min(min((j0 + jj) - last, nxt - (j0 + jj)), 255); // >255: exp==0 both sides
            gp[jj] |= ((uint32_t)gg) << (c * 8);
        }
    }
    uint4* o = reinterpret_cast<uint4*>(ldsrow + j0);
    o[0] = make_uint4(gp[0], gp[1], gp[2], gp[3]);
    o[1] = make_uint4(gp[4], gp[5], gp[6], gp[7]);
}

// ---------------------------------------------------------------------------
// Fused kernel: one block per output row. Phase 1: scan rows i-2..i+2 into
// LDS (5x redundant across blocks; L2-local via batch-per-XCD swizzle).
// Phase 2: CE from pred + vertical min-plus from LDS + weight + block sum +
// one pre-scaled atomicAdd. Rare fallback handles best>9 exactly.
// ---------------------------------------------------------------------------
__global__ __launch_bounds__(256) void k_fused(const float* __restrict__ pred,
                                               const float* __restrict__ target,
                                               float* __restrict__ out) {
    __shared__ uint32_t gl[5][WW];   // 10 KB: packed g for rows i-2..i+2
    __shared__ float red[4];
    __shared__ int flag;

    const int bid0 = blockIdx.x;
    // bijective batch-per-XCD swizzle: XCD x owns batch x, rows in order ->
    // neighbor-row target re-reads are local-L2 hits.
    const int bid = ((bid0 & 7) << 9) | (bid0 >> 3);
    const int i = bid & (HH - 1);
    const int b = bid >> 9;
    const int tid = threadIdx.x, wid = tid >> 6, lane = tid & 63;
    const float* tbase = target + ((size_t)b * CC) * (HH * WW);

    // ---- phase 1: 5 row scans (wave w -> row i-2+w; wave 0 also i+2) ----
    {
        int r = i - 2 + wid;
        if (r >= 0 && r < HH) scan_row(tbase + (size_t)r * WW, lane, gl[wid]);
        if (wid == 0 && i + 2 < HH) scan_row(tbase + (size_t)(i + 2) * WW, lane, gl[4]);
    }
    __syncthreads();

    // ---- phase 2: per-thread 2 pixels ----
    const int j = tid << 1;
    const uint2 gown = *reinterpret_cast<const uint2*>(&gl[2][j]);
    const uint32_t om0 = own_mask(gown.x);
    const uint32_t om1 = own_mask(gown.y);
    float best0 = row_min_sq(gown.x | om0);
    float best1 = row_min_sq(gown.y | om1);

    #pragma unroll
    for (int dk = 1; dk <= 2; ++dk) {
        const float dk2 = (float)(dk * dk);
        if (i - dk >= 0) {
            uint2 v = *reinterpret_cast<const uint2*>(&gl[2 - dk][j]);
            best0 = fminf(best0, row_min_sq(v.x | om0) + dk2);
            best1 = fminf(best1, row_min_sq(v.y | om1) + dk2);
        }
        if (i + dk < HH) {
            uint2 v = *reinterpret_cast<const uint2*>(&gl[2 + dk][j]);
            best0 = fminf(best0, row_min_sq(v.x | om0) + dk2);
            best1 = fminf(best1, row_min_sq(v.y | om1) + dk2);
        }
    }

    // ---- rare exact fallback (further candidates are >= 9) ----
    if (tid == 0) flag = 0;
    __syncthreads();                       // also fences all gl[] reads above
    if (__any(fmaxf(best0, best1) > 9.0f)) { if (lane == 0) flag = 1; }
    __syncthreads();
    if (flag) {                            // block-uniform
        for (int dk = 3; dk < HH; ++dk) {
            const int ru = i - dk, rd = i + dk;
            if (wid == 0 && ru >= 0) scan_row(tbase + (size_t)ru * WW, lane, gl[0]);
            if (wid == 1 && rd < HH) scan_row(tbase + (size_t)rd * WW, lane, gl[1]);
            __syncthreads();
            const float dk2 = (float)(dk * dk);
            if (ru >= 0) {
                uint2 v = *reinterpret_cast<const uint2*>(&gl[0][j]);
                best0 = fminf(best0, row_min_sq(v.x | om0) + dk2);
                best1 = fminf(best1, row_min_sq(v.y | om1) + dk2);
            }
            if (rd < HH) {
                uint2 v = *reinterpret_cast<const uint2*>(&gl[1][j]);
                best0 = fminf(best0, row_min_sq(v.x | om0) + dk2);
                best1 = fminf(best1, row_min_sq(v.y | om1) + dk2);
            }
            __syncthreads();
            if (tid == 0) flag = 0;
            __syncthreads();
            const float nd = (float)((dk + 1) * (dk + 1));
            if (__any(fmaxf(best0, best1) > nd)) { if (lane == 0) flag = 1; }
            __syncthreads();
            if (!flag) break;
            if (ru < 0 && rd >= HH) break;  // exhausted both directions
        }
    }

    // ---- CE from pred; label = zero-byte index of own g word ----
    const float* pb = pred + (((size_t)b * CC) * HH + (size_t)i) * WW + j;
    float a[CC][2];
    #pragma unroll
    for (int c = 0; c < CC; ++c) {
        float2 t = *reinterpret_cast<const float2*>(pb + (size_t)c * (HH * WW));
        a[c][0] = t.x; a[c][1] = t.y;
    }
    const int L0 = __builtin_ctz(om0) >> 3;   // om != 0 always (own class dist 0)
    const int L1 = __builtin_ctz(om1) >> 3;

    float v;
    {
        float m = fmaxf(fmaxf(a[0][0], a[1][0]), fmaxf(a[2][0], a[3][0]));
        float s = __expf(a[0][0] - m) + __expf(a[1][0] - m) +
                  __expf(a[2][0] - m) + __expf(a[3][0] - m);
        float xs = (L0 == 0) ? a[0][0] : (L0 == 1) ? a[1][0] : (L0 == 2) ? a[2][0] : a[3][0];
        float pp = (m + __logf(s)) - xs;
        v = pp * fmaf(10.0f, __expf(-0.02f * best0), 2.0f);   // (1 CE) + (1+10e) weighted
    }
    {
        float m = fmaxf(fmaxf(a[0][1], a[1][1]), fmaxf(a[2][1], a[3][1]));
        float s = __expf(a[0][1] - m) + __expf(a[1][1] - m) +
                  __expf(a[2][1] - m) + __expf(a[3][1] - m);
        float xs = (L1 == 0) ? a[0][1] : (L1 == 1) ? a[1][1] : (L1 == 2) ? a[2][1] : a[3][1];
        float pp = (m + __logf(s)) - xs;
        v += pp * fmaf(10.0f, __expf(-0.02f * best1), 2.0f);
    }

    // ---- block reduction + one pre-scaled atomic per block ----
    #pragma unroll
    for (int off = 32; off > 0; off >>= 1) v += __shfl_down(v, (unsigned)off, 64);
    if (lane == 0) red[wid] = v;
    __syncthreads();
    if (tid == 0) {
        float bs = (red[0] + red[1]) + (red[2] + red[3]);
        atomicAdd(out, bs * (1.0f / (float)NPIX));
    }
}

extern "C" void kernel_launch(void* const* d_in, const int* in_sizes, int n_in,
                              void* d_out, int out_size, void* d_ws, size_t ws_size,
                              hipStream_t stream) {
    const float* pred   = (const float*)d_in[0];
    const float* target = (const float*)d_in[1];
    float* out = (float*)d_out;

    hipMemsetAsync(out, 0, sizeof(float), stream);
    hipLaunchKernelGGL(k_fused, dim3(NBLK), dim3(256), 0, stream, pred, target, out);
}

// Round 5
// 24.850 us; speedup vs baseline: 2.8663x; 2.8663x over previous
//
#include <hip/hip_runtime.h>
#include <stdint.h>

#define HH 512
#define WW 512
#define CC 4
#define BB 8
#define NPIX (BB * HH * WW)    // 2097152
#define SLAB 8
#define NBLK (BB * HH / SLAB)  // 512 blocks, one per 8-row slab

// min over 4 packed u8 row-distances, squared (exact integers in fp32)
__device__ __forceinline__ float row_min_sq(uint32_t v) {
    float c0 = (float)(v & 255u);
    float c1 = (float)((v >> 8) & 255u);
    float c2 = (float)((v >> 16) & 255u);
    float c3 = (float)(v >> 24);
    return fminf(fminf(c0 * c0, c1 * c1), fminf(c2 * c2, c3 * c3));
}

// exact zero-byte mask: byte==0 -> that byte becomes 0xFF (no borrow FPs)
__device__ __forceinline__ uint32_t own_mask(uint32_t v) {
    uint32_t z = (~((v & 0x7F7F7F7Fu) + 0x7F7F7F7Fu)) & ~v & 0x80808080u;
    return (z >> 7) * 255u;
}

// ---------------------------------------------------------------------------
// Wave-cooperative 1D row distance scan: reads target row (4 ch), writes
// packed u8x4 per-class distances to LDS. Lane l owns columns [8l, 8l+8).
// ---------------------------------------------------------------------------
__device__ __forceinline__ void scan_row(const float* __restrict__ trow,
                                         int lane, uint32_t* __restrict__ ldsrow) {
    const int j0 = lane << 3;

    // labels = argmax over channels (one-hot; strict > = first-max semantics)
    int L[8];
    float tm[8];
    #pragma unroll
    for (int c = 0; c < CC; ++c) {
        const float4* p = reinterpret_cast<const float4*>(trow + (size_t)c * (HH * WW) + j0);
        float4 a0 = p[0], a1 = p[1];
        float tv[8] = {a0.x, a0.y, a0.z, a0.w, a1.x, a1.y, a1.z, a1.w};
        #pragma unroll
        for (int jj = 0; jj < 8; ++jj) {
            if (c == 0) { tm[jj] = tv[jj]; L[jj] = 0; }
            else if (tv[jj] > tm[jj]) { tm[jj] = tv[jj]; L[jj] = c; }
        }
    }

    uint32_t gp[8] = {0, 0, 0, 0, 0, 0, 0, 0};
    #pragma unroll
    for (int c = 0; c < CC; ++c) {
        // left: last feature index <= j (local run + wave prefix max)
        int run = -1000000;
        int lastL[8];
        #pragma unroll
        for (int jj = 0; jj < 8; ++jj) { if (L[jj] == c) run = j0 + jj; lastL[jj] = run; }
        int incl = run;
        #pragma unroll
        for (int d = 1; d < 64; d <<= 1) {
            int up = __shfl_up(incl, (unsigned)d, 64);
            if (lane >= d) incl = max(incl, up);
        }
        int excl = __shfl_up(incl, 1u, 64);
        if (lane == 0) excl = -1000000;

        // right: next feature index >= j (reverse prefix min)
        int nrun = 1000000;
        int nxtL[8];
        #pragma unroll
        for (int jj = 7; jj >= 0; --jj) { if (L[jj] == c) nrun = j0 + jj; nxtL[jj] = nrun; }
        int rincl = nrun;
        #pragma unroll
        for (int d = 1; d < 64; d <<= 1) {
            int dn = __shfl_down(rincl, (unsigned)d, 64);
            if (lane < 64 - d) rincl = min(rincl, dn);
        }
        int rexcl = __shfl_down(rincl, 1u, 64);
        if (lane == 63) rexcl = 1000000;

        #pragma unroll
        for (int jj = 0; jj < 8; ++jj) {
            int last = max(lastL[jj], excl);
            int nxt  = min(nxtL[jj], rexcl);
            int gg = min(min((j0 + jj) - last, nxt - (j0 + jj)), 255); // >255: exp==0 both sides
            gp[jj] |= ((uint32_t)gg) << (c * 8);
        }
    }
    uint4* o = reinterpret_cast<uint4*>(ldsrow + j0);
    o[0] = make_uint4(gp[0], gp[1], gp[2], gp[3]);
    o[1] = make_uint4(gp[4], gp[5], gp[6], gp[7]);
}

// ---------------------------------------------------------------------------
// Slab-fused kernel: 512 threads (8 waves) own 8 output rows. Phase 1: scan
// the 12 covering target rows into LDS (1.5x redundancy; slab-adjacent
// re-reads are L2-local via batch-per-XCD chunked swizzle). Phase 2:
// vertical min-plus (+-2) from LDS, rare exact band fallback, CE from pred,
// weight, block sum -> partial[]. NO same-address atomics (rounds 2/4
// showed single-address device atomics from many blocks cost ~60-90 us).
// ---------------------------------------------------------------------------
__global__ __launch_bounds__(512) void k_fused(const float* __restrict__ pred,
                                               const float* __restrict__ target,
                                               float* __restrict__ partial) {
    __shared__ uint32_t gl[12][WW];   // 24 KB: la = absrow - (i0-2)
    __shared__ float red[8];
    __shared__ int sflag;

    const int bid0 = blockIdx.x;
    // bijective XCD-chunked swizzle (512 = 8 XCDs x 64): XCD x owns batch x,
    // slabs in order -> boundary target rows are local-L2 hits.
    const int bid = ((bid0 & 7) << 6) | (bid0 >> 3);
    const int b  = bid >> 6;
    const int i0 = (bid & 63) << 3;
    const int tid = threadIdx.x, wid = tid >> 6, lane = tid & 63;
    const float* tbase = target + (size_t)b * CC * (HH * WW);

    // ---- phase 1: 12 scans over 8 waves ----
    {
        int r = i0 - 2 + wid;                      // la = wid
        if (r >= 0 && r < HH) scan_row(tbase + (size_t)r * WW, lane, gl[wid]);
        if (wid < 4) {
            int r2 = i0 + 6 + wid;                 // la = 8 + wid
            if (r2 < HH) scan_row(tbase + (size_t)r2 * WW, lane, gl[8 + wid]);
        }
    }
    if (tid == 0) sflag = 0;
    __syncthreads();

    // ---- phase 2: group grp=tid>>8 handles rows s=grp*4+q (q=0..3), 2 px ----
    const int grp = tid >> 8;
    const int j   = (tid & 255) << 1;
    float    bs[4][2];
    uint32_t om[4][2];
    #pragma unroll
    for (int q = 0; q < 4; ++q) {
        const int s  = (grp << 2) + q;
        const int la = s + 2;
        uint2 gown = *reinterpret_cast<const uint2*>(&gl[la][j]);
        uint32_t o0 = own_mask(gown.x), o1 = own_mask(gown.y);
        float b0 = row_min_sq(gown.x | o0);
        float b1 = row_min_sq(gown.y | o1);
        #pragma unroll
        for (int dk = 1; dk <= 2; ++dk) {
            const float dk2 = (float)(dk * dk);
            if (i0 + s - dk >= 0) {
                uint2 v = *reinterpret_cast<const uint2*>(&gl[la - dk][j]);
                b0 = fminf(b0, row_min_sq(v.x | o0) + dk2);
                b1 = fminf(b1, row_min_sq(v.y | o1) + dk2);
            }
            if (i0 + s + dk < HH) {
                uint2 v = *reinterpret_cast<const uint2*>(&gl[la + dk][j]);
                b0 = fminf(b0, row_min_sq(v.x | o0) + dk2);
                b1 = fminf(b1, row_min_sq(v.y | o1) + dk2);
            }
        }
        bs[q][0] = b0; bs[q][1] = b1; om[q][0] = o0; om[q][1] = o1;
    }

    {
        float mx = 0.f;
        #pragma unroll
        for (int q = 0; q < 4; ++q) mx = fmaxf(mx, fmaxf(bs[q][0], bs[q][1]));
        if (__any(mx > 9.0f)) { if (lane == 0) sflag = 1; }
    }
    __syncthreads();

    // ---- rare exact fallback: band rescans, reusing gl[0..7] ----
    if (sflag) {
        for (int dk = 3; dk < HH; ++dk) {
            { int rr = i0 + wid - dk;               // up band -> gl[wid]
              if (rr >= 0 && rr < HH) scan_row(tbase + (size_t)rr * WW, lane, gl[wid]); }
            __syncthreads();
            const float dk2 = (float)(dk * dk);
            #pragma unroll
            for (int q = 0; q < 4; ++q) {
                const int s = (grp << 2) + q;
                if (i0 + s - dk >= 0) {
                    uint2 v = *reinterpret_cast<const uint2*>(&gl[s][j]);
                    bs[q][0] = fminf(bs[q][0], row_min_sq(v.x | om[q][0]) + dk2);
                    bs[q][1] = fminf(bs[q][1], row_min_sq(v.y | om[q][1]) + dk2);
                }
            }
            __syncthreads();
            { int rr = i0 + wid + dk;               // down band -> gl[wid]
              if (rr < HH) scan_row(tbase + (size_t)rr * WW, lane, gl[wid]); }
            __syncthreads();
            #pragma unroll
            for (int q = 0; q < 4; ++q) {
                const int s = (grp << 2) + q;
                if (i0 + s + dk < HH) {
                    uint2 v = *reinterpret_cast<const uint2*>(&gl[s][j]);
                    bs[q][0] = fminf(bs[q][0], row_min_sq(v.x | om[q][0]) + dk2);
                    bs[q][1] = fminf(bs[q][1], row_min_sq(v.y | om[q][1]) + dk2);
                }
            }
            __syncthreads();
            if (tid == 0) sflag = 0;
            __syncthreads();
            float nthr = (float)((dk + 1) * (dk + 1));
            float mx = 0.f;
            #pragma unroll
            for (int q = 0; q < 4; ++q) mx = fmaxf(mx, fmaxf(bs[q][0], bs[q][1]));
            if (__any(mx > nthr)) { if (lane == 0) sflag = 1; }
            __syncthreads();
            if (!sflag) break;
            if (i0 + SLAB - 1 - dk < 0 && i0 + dk >= HH) break;  // exhausted
        }
    }

    // ---- CE from pred (label = zero-byte of own g word) + weight + sum ----
    const float* pb = pred + (((size_t)b * CC) * HH + (size_t)i0) * WW + j;
    float vacc = 0.f;
    #pragma unroll
    for (int q = 0; q < 4; ++q) {
        const int s = (grp << 2) + q;
        const float* pr = pb + (size_t)s * WW;
        float a0[CC], a1[CC];
        #pragma unroll
        for (int c = 0; c < CC; ++c) {
            float2 t = *reinterpret_cast<const float2*>(pr + (size_t)c * (HH * WW));
            a0[c] = t.x; a1[c] = t.y;
        }
        const int L0 = __builtin_ctz(om[q][0]) >> 3;  // om != 0 (own dist is 0)
        const int L1 = __builtin_ctz(om[q][1]) >> 3;
        {
            float m = fmaxf(fmaxf(a0[0], a0[1]), fmaxf(a0[2], a0[3]));
            float ssum = __expf(a0[0] - m) + __expf(a0[1] - m) +
                         __expf(a0[2] - m) + __expf(a0[3] - m);
            float xs = (L0 == 0) ? a0[0] : (L0 == 1) ? a0[1] : (L0 == 2) ? a0[2] : a0[3];
            float pp = (m + __logf(ssum)) - xs;
            vacc += pp * fmaf(10.0f, __expf(-0.02f * bs[q][0]), 2.0f);
        }
        {
            float m = fmaxf(fmaxf(a1[0], a1[1]), fmaxf(a1[2], a1[3]));
            float ssum = __expf(a1[0] - m) + __expf(a1[1] - m) +
                         __expf(a1[2] - m) + __expf(a1[3] - m);
            float xs = (L1 == 0) ? a1[0] : (L1 == 1) ? a1[1] : (L1 == 2) ? a1[2] : a1[3];
            float pp = (m + __logf(ssum)) - xs;
            vacc += pp * fmaf(10.0f, __expf(-0.02f * bs[q][1]), 2.0f);
        }
    }

    // ---- block reduction -> partial[] (no atomics) ----
    #pragma unroll
    for (int off = 32; off > 0; off >>= 1) vacc += __shfl_down(vacc, (unsigned)off, 64);
    if (lane == 0) red[wid] = vacc;
    __syncthreads();
    if (tid == 0) {
        float bsum = ((red[0] + red[1]) + (red[2] + red[3]))
                   + ((red[4] + red[5]) + (red[6] + red[7]));
        partial[blockIdx.x] = bsum;
    }
}

// ---------------------------------------------------------------------------
// K_red: deterministic double-precision final reduction over 512 partials.
// ---------------------------------------------------------------------------
__global__ __launch_bounds__(256) void k_red(const float* __restrict__ partial,
                                             float* __restrict__ out) {
    __shared__ double sd[256];
    double a = (double)partial[threadIdx.x] + (double)partial[threadIdx.x + 256];
    sd[threadIdx.x] = a;
    __syncthreads();
    #pragma unroll
    for (int s = 128; s > 0; s >>= 1) {
        if (threadIdx.x < s) sd[threadIdx.x] += sd[threadIdx.x + s];
        __syncthreads();
    }
    if (threadIdx.x == 0) out[0] = (float)(sd[0] * (1.0 / (double)NPIX));
}

extern "C" void kernel_launch(void* const* d_in, const int* in_sizes, int n_in,
                              void* d_out, int out_size, void* d_ws, size_t ws_size,
                              hipStream_t stream) {
    const float* pred   = (const float*)d_in[0];
    const float* target = (const float*)d_in[1];
    float* partial = (float*)d_ws;     // 2 KB
    float* out = (float*)d_out;

    hipLaunchKernelGGL(k_fused, dim3(NBLK), dim3(512), 0, stream, pred, target, partial);
    hipLaunchKernelGGL(k_red, dim3(1), dim3(256), 0, stream, partial, out);
}